// Round 1
// 241.010 us; speedup vs baseline: 1.1426x; 1.1426x over previous
//
#include <hip/hip_runtime.h>
#include <hip/hip_bf16.h>

// Problem constants
#define B_   2
#define N_   512
#define M_   512
#define D_   128    // Dq = Dk = Dv
#define DE_  64
#define H_   8
#define O_   32
#define OUT_ 128
#define DKE_ 192    // Dk + De
#define MP_  516    // padded M for attn_s rows

typedef unsigned short u16;
typedef unsigned int   u32;
typedef short bf16x8 __attribute__((ext_vector_type(8)));
typedef float floatx4 __attribute__((ext_vector_type(4)));

__device__ __forceinline__ u32 pk2bf(float a, float b) {
    __hip_bfloat162 h = __float22bfloat162_rn(make_float2(a, b));
    return *reinterpret_cast<u32*>(&h);
}
__device__ __forceinline__ u16 f2bf(float a) {
    __hip_bfloat16 h = __float2bfloat16(a);
    return *reinterpret_cast<u16*>(&h);
}
__device__ __forceinline__ float bf2f(u16 x) {
    return __uint_as_float(((u32)x) << 16);
}
// pack 8 fp32 (two float4) -> bf16x8 fragment
__device__ __forceinline__ bf16x8 cvt8(const float4 a, const float4 b) {
    union { u32 u[4]; bf16x8 v; } r;
    r.u[0] = pk2bf(a.x, a.y); r.u[1] = pk2bf(a.z, a.w);
    r.u[2] = pk2bf(b.x, b.y); r.u[3] = pk2bf(b.z, b.w);
    return r.v;
}

// ---------------------------------------------------------------------------
// Merged projection kernel, grid = 320 x 256 threads.
// Blocks 0..127   : per 8 (b,n) rows -> qE bf16 [row][h*192+j]
// Blocks 128..255 : per 8 (b,m) rows -> vP bf16 [b][m>>3][col=h*32+o][m&7]
//                   (PV-coalesced tiling: lane-consecutive cols are contiguous)
// Blocks 256..319 : keyF: key in bf16 MFMA-B-fragment order
//                   keyF[b][tl][kk][lane][8], lane=(q<<4)|br,
//                   element j = key[b][tl*16+br][kk*32+q*8+j]
// ---------------------------------------------------------------------------
__global__ __launch_bounds__(256) void k_proj(
    const float* __restrict__ query, const float* __restrict__ Wq,
    const float* __restrict__ Wk,
    const float* __restrict__ value, const float* __restrict__ Wv,
    const float* __restrict__ key,
    u16* __restrict__ qE, u16* __restrict__ vP, u16* __restrict__ keyF)
{
    const int t = threadIdx.x;
    __shared__ float Xs[8][D_];
    __shared__ float qh[8][H_ * O_];

    if (blockIdx.x < 128) {
        const int r0 = blockIdx.x * 8;
        reinterpret_cast<float4*>(&Xs[0][0])[t] =
            reinterpret_cast<const float4*>(query + (size_t)r0 * D_)[t];
        __syncthreads();
        {
            float acc[8] = {0,0,0,0,0,0,0,0};
            const float* wcol = Wq + (t >> 5) * (D_ * O_) + (t & 31);
            for (int k = 0; k < D_; k += 4) {
                const float w0 = wcol[(k+0) * O_];
                const float w1 = wcol[(k+1) * O_];
                const float w2 = wcol[(k+2) * O_];
                const float w3 = wcol[(k+3) * O_];
#pragma unroll
                for (int r = 0; r < 8; ++r) {
                    const float4 x = *reinterpret_cast<const float4*>(&Xs[r][k]);
                    acc[r] += x.x * w0 + x.y * w1 + x.z * w2 + x.w * w3;
                }
            }
#pragma unroll
            for (int r = 0; r < 8; ++r) qh[r][t] = acc[r] * 0.17677669529663687f;
        }
        __syncthreads();

        for (int s = 0; s < 6; ++s) {
            const int hj = t + 256 * s;
            const int h  = hj / DKE_;
            float w[O_];
#pragma unroll
            for (int i = 0; i < O_ / 4; ++i) {
                const float4 x = reinterpret_cast<const float4*>(Wk + (size_t)hj * O_)[i];
                w[4*i] = x.x; w[4*i+1] = x.y; w[4*i+2] = x.z; w[4*i+3] = x.w;
            }
#pragma unroll
            for (int r = 0; r < 8; ++r) {
                const float* qrow = &qh[r][h * O_];
                float a = 0.f;
#pragma unroll
                for (int i = 0; i < O_ / 4; ++i) {
                    const float4 qx = *reinterpret_cast<const float4*>(qrow + 4*i);
                    a += qx.x * w[4*i] + qx.y * w[4*i+1] + qx.z * w[4*i+2] + qx.w * w[4*i+3];
                }
                qE[(size_t)(r0 + r) * (H_ * DKE_) + hj] = f2bf(a);
            }
        }
    } else if (blockIdx.x < 256) {
        const int r0 = (blockIdx.x - 128) * 8;          // global (b,m) row
        reinterpret_cast<float4*>(&Xs[0][0])[t] =
            reinterpret_cast<const float4*>(value + (size_t)r0 * D_)[t];
        __syncthreads();

        float acc[8] = {0,0,0,0,0,0,0,0};
        const float* wcol = Wv + (t >> 5) * (D_ * O_) + (t & 31);
        for (int k = 0; k < D_; k += 4) {
            const float w0 = wcol[(k+0) * O_];
            const float w1 = wcol[(k+1) * O_];
            const float w2 = wcol[(k+2) * O_];
            const float w3 = wcol[(k+3) * O_];
#pragma unroll
            for (int r = 0; r < 8; ++r) {
                const float4 x = *reinterpret_cast<const float4*>(&Xs[r][k]);
                acc[r] += x.x * w0 + x.y * w1 + x.z * w2 + x.w * w3;
            }
        }
        // PV-coalesced bf16 write: vP[b][m0>>3][col=t][0..7] as one 16 B store
        const int bb = r0 >> 9, m0 = r0 & 511;
        union { u32 u[4]; uint4 q; } pk;
        pk.u[0] = pk2bf(acc[0], acc[1]);
        pk.u[1] = pk2bf(acc[2], acc[3]);
        pk.u[2] = pk2bf(acc[4], acc[5]);
        pk.u[3] = pk2bf(acc[6], acc[7]);
        *reinterpret_cast<uint4*>(
            vP + ((((size_t)bb * 64) + (m0 >> 3)) * 256 + t) * 8) = pk.q;
    } else {
        // keyF builder: one block per (b, m-tile)
        const int kb = blockIdx.x - 256;                // 0..63
        const int bb = kb >> 5, tl = kb & 31;
        const int kk = t >> 6, l = t & 63;
        const int br = l & 15, q = l >> 4;
        const float* src = key + ((size_t)bb * M_ + tl * 16 + br) * D_ + kk * 32 + q * 8;
        const float4 f0 = *reinterpret_cast<const float4*>(src);
        const float4 f1 = *reinterpret_cast<const float4*>(src + 4);
        union { bf16x8 v; uint4 u; } r;
        r.v = cvt8(f0, f1);
        *reinterpret_cast<uint4*>(
            keyF + ((((size_t)bb * 32 + tl) * 4 + kk) * 64 + l) * 8) = r.u;
    }
}

// ---------------------------------------------------------------------------
// k_attn: per (b,n). Logits via MFMA 16x16x32 bf16.
//   - key part: B-fragments loaded COALESCED from pre-permuted keyF (bf16).
//   - edge part: 16m x 64 tile (contiguous 4 KB) loaded coalesced, converted
//     to bf16 in regs, ds_write straight into fragment-layout LDS
//     (wave-private double buffer, linear conflict-free ds_read_b128),
//     1-tile register prefetch.
// Then softmax, bf16 PV streamed coalesced from vP, projection.
// grid = 1024 x 256 (4 waves x 8 m-tiles each); 4 blocks/CU = 1 full round.
// ---------------------------------------------------------------------------
__global__ __launch_bounds__(256, 4) void k_attn(
    const float* __restrict__ edge,
    const u16* __restrict__ qE, const u16* __restrict__ vP,
    const u16* __restrict__ keyF,
    const float* __restrict__ Wp, const float* __restrict__ bias,
    float* __restrict__ out)
{
    const int idx  = blockIdx.x;          // b*N + n
    const int b    = idx >> 9;
    const int t    = threadIdx.x;
    const int lane = t & 63;
    const int wv   = t >> 6;

    __shared__ __attribute__((aligned(16))) float attn_s[H_][MP_]; // 16.5 KB
    __shared__ __attribute__((aligned(16))) u16 elds[4][2][2][64][8]; // 16 KB
    __shared__ float mh_s[H_ * O_];
    __shared__ float part_s[2][OUT_];

    const int br = lane & 15;             // B column / m within tile; A row (head)
    const int q  = lane >> 4;             // k-quad

    // ---- A fragments: lane holds qE[row=br][kk*32 + q*8 + 0..7], rows>=8 zero
    bf16x8 afr[6];
    if (br < 8) {
        const u16* ab = qE + (size_t)idx * (H_ * DKE_) + br * DKE_;
#pragma unroll
        for (int kk = 0; kk < 6; ++kk)
            afr[kk] = *reinterpret_cast<const bf16x8*>(ab + kk * 32 + q * 8);
    } else {
#pragma unroll
        for (int kk = 0; kk < 6; ++kk) afr[kk] = bf16x8{0,0,0,0,0,0,0,0};
    }

    const float* eb  = edge + (size_t)idx * (M_ * DE_);
    const u16*   kfb = keyF + (size_t)b * (32 * 4 * 64 * 8);

    // ---- logits: 8 m-tiles per wave; edge staged via fragment-layout LDS ----
    float4 ef[4];
    {   // prologue: coalesced load of this wave's first tile (contig 4 KB)
        const float* tb = eb + (size_t)wv * 1024;
#pragma unroll
        for (int i = 0; i < 4; ++i)
            ef[i] = reinterpret_cast<const float4*>(tb)[i * 64 + lane];
    }
    for (int it = 0; it < 8; ++it) {
        const int tl  = it * 4 + wv;
        const int buf = it & 1;
        // stage current tile into fragment layout: chunk c=(row=c>>4, col4=c&15)
        // -> frag[kk=col4>>3][lane'=((col4>>1)&3)*16+row][half=col4&1]
#pragma unroll
        for (int i = 0; i < 4; ++i) {
            const int c    = i * 64 + lane;
            const int row  = c >> 4, col4 = c & 15;
            uint2 p;
            p.x = pk2bf(ef[i].x, ef[i].y);
            p.y = pk2bf(ef[i].z, ef[i].w);
            *reinterpret_cast<uint2*>(
                &elds[wv][buf][col4 >> 3][(((col4 >> 1) & 3) << 4) + row][(col4 & 1) * 4]) = p;
        }
        // prefetch next tile (coalesced)
        if (it < 7) {
            const float* tb = eb + (size_t)(tl + 4) * 1024;
#pragma unroll
            for (int i = 0; i < 4; ++i)
                ef[i] = reinterpret_cast<const float4*>(tb)[i * 64 + lane];
        }
        // key MFMAs: coalesced fragment loads from keyF
        floatx4 acc = {0.f, 0.f, 0.f, 0.f};
        const u16* kf = kfb + (size_t)tl * 4 * 512 + lane * 8;
#pragma unroll
        for (int kk = 0; kk < 4; ++kk) {
            const bf16x8 bfr = *reinterpret_cast<const bf16x8*>(kf + kk * 512);
            acc = __builtin_amdgcn_mfma_f32_16x16x32_bf16(afr[kk], bfr, acc, 0, 0, 0);
        }
        // edge MFMAs: linear conflict-free LDS fragment reads
#pragma unroll
        for (int kk = 0; kk < 2; ++kk) {
            const bf16x8 bfr = *reinterpret_cast<const bf16x8*>(&elds[wv][buf][kk][lane][0]);
            acc = __builtin_amdgcn_mfma_f32_16x16x32_bf16(afr[4 + kk], bfr, acc, 0, 0, 0);
        }
        if (q < 2) {
#pragma unroll
            for (int i = 0; i < 4; ++i)
                attn_s[q * 4 + i][tl * 16 + br] = acc[i];
        }
    }
    __syncthreads();

    // ---- softmax over m per head (32 lanes own one head row) ----
    {
        const int h = t >> 5, ml = t & 31;
        float mx = -3.4e38f;
#pragma unroll 2
        for (int j = 0; j < 16; ++j) mx = fmaxf(mx, attn_s[h][ml + 32 * j]);
#pragma unroll
        for (int mask = 16; mask >= 1; mask >>= 1) mx = fmaxf(mx, __shfl_xor(mx, mask, 64));
        float sum = 0.f;
#pragma unroll 2
        for (int j = 0; j < 16; ++j) {
            const int m = ml + 32 * j;
            const float p = __expf(attn_s[h][m] - mx);
            attn_s[h][m] = p;
            sum += p;
        }
#pragma unroll
        for (int mask = 16; mask >= 1; mask >>= 1) sum += __shfl_xor(sum, mask, 64);
        const float inv = 1.f / sum;
#pragma unroll 2
        for (int j = 0; j < 16; ++j) attn_s[h][ml + 32 * j] *= inv;
    }
    __syncthreads();

    // ---- mh[h][o]: thread=(h,o)=t streams vP[b][m>>3][t][0..7] (coalesced) ----
    {
        const int hh = t >> 5;
        const u16* vb = vP + (size_t)b * (64 * 256 * 8);
        float a0 = 0.f, a1 = 0.f;
        for (int m0 = 0; m0 < M_; m0 += 8) {
            const bf16x8 v8 = *reinterpret_cast<const bf16x8*>(
                vb + ((size_t)(m0 >> 3) * 256 + t) * 8);
            const float4 w0 = *reinterpret_cast<const float4*>(&attn_s[hh][m0]);
            const float4 w1 = *reinterpret_cast<const float4*>(&attn_s[hh][m0 + 4]);
            a0 += w0.x * bf2f((u16)v8[0]) + w0.y * bf2f((u16)v8[1])
                + w0.z * bf2f((u16)v8[2]) + w0.w * bf2f((u16)v8[3]);
            a1 += w1.x * bf2f((u16)v8[4]) + w1.y * bf2f((u16)v8[5])
                + w1.z * bf2f((u16)v8[6]) + w1.w * bf2f((u16)v8[7]);
        }
        mh_s[t] = a0 + a1;
    }
    __syncthreads();

    // ---- out[c] = bias[c] + sum_j mh[j] * Wp[j*128 + c] ----
    {
        const int half = t >> 7;
        const int c = t & 127;
        float acc = 0.f;
        const int j0 = half * 128;
#pragma unroll 8
        for (int jj = 0; jj < 128; ++jj)
            acc += mh_s[j0 + jj] * Wp[(size_t)(j0 + jj) * OUT_ + c];
        part_s[half][c] = acc;
    }
    __syncthreads();
    if (t < OUT_)
        out[(size_t)idx * OUT_ + t] = part_s[0][t] + part_s[1][t] + bias[t];
}

// ---------------------------------------------------------------------------
extern "C" void kernel_launch(void* const* d_in, const int* in_sizes, int n_in,
                              void* d_out, int out_size, void* d_ws, size_t ws_size,
                              hipStream_t stream)
{
    const float* query = (const float*)d_in[0];   // [B,N,128]
    const float* key   = (const float*)d_in[1];   // [B,M,128]
    const float* value = (const float*)d_in[2];   // [B,M,128]
    const float* edge  = (const float*)d_in[3];   // [B,N,M,64]
    const float* Wq    = (const float*)d_in[4];   // [8,128,32]
    const float* Wk    = (const float*)d_in[5];   // [8,192,32]
    const float* Wv    = (const float*)d_in[6];   // [8,128,32]
    const float* Wp    = (const float*)d_in[7];   // [8,32,128]
    const float* bias  = (const float*)d_in[8];   // [128]
    float* out = (float*)d_out;                   // [B,N,128] fp32

    u16* qE_ws = (u16*)d_ws;                                  // 1024*1536*2 = 3.1 MB
    u16* vP_ws = qE_ws + (size_t)B_ * N_ * H_ * DKE_;         // 2*64*256*8*2 = 512 KB
    u16* kF_ws = vP_ws + (size_t)B_ * 64 * 256 * 8;           // 2*32*4*64*8*2 = 256 KB

    k_proj<<<320,  256, 0, stream>>>(query, Wq, Wk, value, Wv, key, qE_ws, vP_ws, kF_ws);
    k_attn<<<1024, 256, 0, stream>>>(edge, qE_ws, vP_ws, kF_ws, Wp, bias, out);
}